// Round 1
// baseline (3283.741 us; speedup 1.0000x reference)
//
#include <hip/hip_runtime.h>
#include <hip/hip_bf16.h>
#include <math.h>

// ---------------------------------------------------------------------------
// DualHeadGAT: 2-layer GAT (H1=4,C=64 then H=1,C=64) + linear scoring head.
// N=50000, IN=128, E=800000 (+N self loops). All f32, edge_index int32.
// Softmax normalization deferred to the node epilogue => single edge pass per
// layer (exact: softmax is shift/scale invariant; |e|<=~12 so exp() is safe).
// ---------------------------------------------------------------------------

#define LRELU_SLOPE 0.2f

// ---------------- f32 tiled GEMM: C[M,N] = A[M,K] @ B[K,N] -----------------
// 64x64 tile, BK=16, 256 threads, 4x4 micro-tile per thread.
__global__ __launch_bounds__(256)
void gemm64(const float* __restrict__ A, const float* __restrict__ B,
            float* __restrict__ C, int M, int N, int K)
{
    __shared__ float As[16][65];   // A^T tile (k-major), +1 pad
    __shared__ float Bs[16][64];
    const int tid = threadIdx.x;
    const int tx = tid & 15, ty = tid >> 4;
    const int m0 = blockIdx.x * 64, n0 = blockIdx.y * 64;
    float acc[4][4] = {};

    for (int kk = 0; kk < K; kk += 16) {
        {   // A tile: 64 rows x 16 k
            int r = tid >> 2;             // 0..63
            int c = (tid & 3) << 2;       // 0,4,8,12
            int gr = m0 + r;
            float4 v = make_float4(0.f, 0.f, 0.f, 0.f);
            if (gr < M) v = *(const float4*)(A + (size_t)gr * K + kk + c);
            As[c + 0][r] = v.x; As[c + 1][r] = v.y;
            As[c + 2][r] = v.z; As[c + 3][r] = v.w;
        }
        {   // B tile: 16 k x 64 cols
            int r = tid >> 4;             // 0..15
            int c = (tid & 15) << 2;      // 0..60
            float4 v = *(const float4*)(B + (size_t)(kk + r) * N + n0 + c);
            Bs[r][c + 0] = v.x; Bs[r][c + 1] = v.y;
            Bs[r][c + 2] = v.z; Bs[r][c + 3] = v.w;
        }
        __syncthreads();
        #pragma unroll
        for (int k = 0; k < 16; ++k) {
            float a[4], b[4];
            #pragma unroll
            for (int i = 0; i < 4; ++i) a[i] = As[k][ty + 16 * i];
            #pragma unroll
            for (int j = 0; j < 4; ++j) b[j] = Bs[k][tx + 16 * j];
            #pragma unroll
            for (int i = 0; i < 4; ++i)
                #pragma unroll
                for (int j = 0; j < 4; ++j)
                    acc[i][j] = fmaf(a[i], b[j], acc[i][j]);
        }
        __syncthreads();
    }
    #pragma unroll
    for (int i = 0; i < 4; ++i) {
        int m = m0 + ty + 16 * i;
        if (m >= M) continue;
        #pragma unroll
        for (int j = 0; j < 4; ++j)
            C[(size_t)m * N + n0 + tx + 16 * j] = acc[i][j];
    }
}

// ---------------- attention dots: a_src/a_dst [N,H], C=64 ------------------
// one wave per (n,h) row of h (layout [N, H*64]).
__global__ __launch_bounds__(256)
void att_dots(const float* __restrict__ h, const float* __restrict__ atts,
              const float* __restrict__ attd, float* __restrict__ as_,
              float* __restrict__ ad_, int rows /*N*H*/, int H)
{
    int w = (blockIdx.x * blockDim.x + threadIdx.x) >> 6;
    int lane = threadIdx.x & 63;
    if (w >= rows) return;
    int hh = w & (H - 1);                      // H is 1 or 4 (pow2)
    float v = h[(size_t)w * 64 + lane];
    float s = v * atts[hh * 64 + lane];
    float d = v * attd[hh * 64 + lane];
    #pragma unroll
    for (int off = 32; off; off >>= 1) {
        s += __shfl_down(s, off);
        d += __shfl_down(d, off);
    }
    if (lane == 0) { as_[w] = s; ad_[w] = d; }
}

// ---------------- fused edge pass, layer 1 (H=4, HC=256) -------------------
// wave per edge; lane handles float4 of h1[src]; accumulates unnormalized
// p*h into out[dst] and p into denom[dst,head].
__global__ __launch_bounds__(256)
void edge_pass_l1(const int* __restrict__ esrc, const int* __restrict__ edst,
                  const float* __restrict__ h1, const float* __restrict__ as_,
                  const float* __restrict__ ad_, float* __restrict__ out,
                  float* __restrict__ denom, int E, int N)
{
    int w = (blockIdx.x * blockDim.x + threadIdx.x) >> 6;
    int lane = threadIdx.x & 63;
    int ET = E + N;
    if (w >= ET) return;
    int s, d;
    if (w < E) { s = esrc[w]; d = edst[w]; }
    else       { s = d = w - E; }
    int c0 = lane << 2;          // 0..252
    int head = lane >> 4;        // 0..3
    float e = as_[s * 4 + head] + ad_[d * 4 + head];
    e = e > 0.f ? e : LRELU_SLOPE * e;
    float p = expf(e);
    const float4 v = *(const float4*)(h1 + (size_t)s * 256 + c0);
    float* o = out + (size_t)d * 256 + c0;
    atomicAdd(o + 0, p * v.x);
    atomicAdd(o + 1, p * v.y);
    atomicAdd(o + 2, p * v.z);
    atomicAdd(o + 3, p * v.w);
    if ((lane & 15) == 0) atomicAdd(denom + d * 4 + head, p);
}

// ---------------- fused edge pass, layer 2 (H=1, C=64) ---------------------
__global__ __launch_bounds__(256)
void edge_pass_l2(const int* __restrict__ esrc, const int* __restrict__ edst,
                  const float* __restrict__ h2, const float* __restrict__ as_,
                  const float* __restrict__ ad_, float* __restrict__ out,
                  float* __restrict__ denom, int E, int N)
{
    int w = (blockIdx.x * blockDim.x + threadIdx.x) >> 6;
    int lane = threadIdx.x & 63;
    int ET = E + N;
    if (w >= ET) return;
    int s, d;
    if (w < E) { s = esrc[w]; d = edst[w]; }
    else       { s = d = w - E; }
    float e = as_[s] + ad_[d];
    e = e > 0.f ? e : LRELU_SLOPE * e;
    float p = expf(e);
    float v = h2[(size_t)s * 64 + lane];
    atomicAdd(out + (size_t)d * 64 + lane, p * v);
    if (lane == 0) atomicAdd(denom + d, p);
}

// -------- layer-1 epilogue: out = elu(out/denom + b1), in place ------------
__global__ __launch_bounds__(256)
void norm_bias_elu_l1(float* __restrict__ io, const float* __restrict__ denom,
                      const float* __restrict__ bias, int total /*N*256*/)
{
    int idx = blockIdx.x * blockDim.x + threadIdx.x;
    if (idx >= total) return;
    int n = idx >> 8;            // /256
    int c = idx & 255;
    float den = denom[n * 4 + (c >> 6)] + 1e-16f;
    float v = io[idx] / den + bias[c];
    io[idx] = v > 0.f ? v : expm1f(v);
}

// -------- layer-2 epilogue: h = elu(acc/denom + b2); scores = h.Ws + bs ----
__global__ __launch_bounds__(256)
void epilogue2(float* __restrict__ h /* d_out [N,64] accum */,
               const float* __restrict__ denom, const float* __restrict__ b2,
               const float* __restrict__ Ws, const float* __restrict__ bs,
               float* __restrict__ scores, int N)
{
    int w = (blockIdx.x * blockDim.x + threadIdx.x) >> 6;
    int lane = threadIdx.x & 63;
    if (w >= N) return;
    float den = denom[w] + 1e-16f;
    float v = h[(size_t)w * 64 + lane] / den + b2[lane];
    v = v > 0.f ? v : expm1f(v);
    h[(size_t)w * 64 + lane] = v;
    float sc = v * Ws[lane];
    #pragma unroll
    for (int off = 32; off; off >>= 1) sc += __shfl_down(sc, off);
    if (lane == 0) scores[w] = sc + bs[0];
}

// ---------------------------------------------------------------------------
extern "C" void kernel_launch(void* const* d_in, const int* in_sizes, int n_in,
                              void* d_out, int out_size, void* d_ws, size_t ws_size,
                              hipStream_t stream)
{
    const float* x    = (const float*)d_in[0];
    const int*   ei   = (const int*)d_in[1];
    const float* W1   = (const float*)d_in[2];
    const float* as1w = (const float*)d_in[3];
    const float* ad1w = (const float*)d_in[4];
    const float* b1   = (const float*)d_in[5];
    const float* W2   = (const float*)d_in[6];
    const float* as2w = (const float*)d_in[7];
    const float* ad2w = (const float*)d_in[8];
    const float* b2   = (const float*)d_in[9];
    const float* Ws   = (const float*)d_in[10];
    const float* bs   = (const float*)d_in[11];

    const int N  = in_sizes[0] / 128;   // 50000
    const int E  = in_sizes[1] / 2;     // 800000
    const int ET = E + N;
    const int* esrc = ei;
    const int* edst = ei + E;

    // workspace layout (floats)
    float* ws   = (float*)d_ws;
    float* h1   = ws;                              // N*256
    float* out1 = h1   + (size_t)N * 256;          // N*256 (becomes h_l1)
    float* as1  = out1 + (size_t)N * 256;          // N*4
    float* ad1  = as1  + (size_t)N * 4;            // N*4
    float* den1 = ad1  + (size_t)N * 4;            // N*4
    float* h2   = den1 + (size_t)N * 4;            // N*64
    float* as2  = h2   + (size_t)N * 64;           // N
    float* ad2  = as2  + (size_t)N;                // N
    float* den2 = ad2  + (size_t)N;                // N

    float* hout   = (float*)d_out;                 // N*64
    float* scores = hout + (size_t)N * 64;         // N

    // zero accumulators (ws/d_out are poisoned, and graph replays reuse them)
    hipMemsetAsync(out1, 0, (size_t)N * 256 * sizeof(float), stream);
    hipMemsetAsync(den1, 0, (size_t)N * 4 * sizeof(float), stream);
    hipMemsetAsync(den2, 0, (size_t)N * sizeof(float), stream);
    hipMemsetAsync(d_out, 0, (size_t)out_size * sizeof(float), stream);

    // ---------------- layer 1 ----------------
    {
        dim3 grid((N + 63) / 64, 256 / 64);
        gemm64<<<grid, 256, 0, stream>>>(x, W1, h1, N, 256, 128);
    }
    att_dots<<<((size_t)N * 4 * 64 + 255) / 256, 256, 0, stream>>>(
        h1, as1w, ad1w, as1, ad1, N * 4, 4);
    edge_pass_l1<<<(ET + 3) / 4, 256, 0, stream>>>(
        esrc, edst, h1, as1, ad1, out1, den1, E, N);
    norm_bias_elu_l1<<<((size_t)N * 256 + 255) / 256, 256, 0, stream>>>(
        out1, den1, b1, N * 256);

    // ---------------- layer 2 ----------------
    {
        dim3 grid((N + 63) / 64, 1);
        gemm64<<<grid, 256, 0, stream>>>(out1, W2, h2, N, 64, 256);
    }
    att_dots<<<((size_t)N * 64 + 255) / 256, 256, 0, stream>>>(
        h2, as2w, ad2w, as2, ad2, N, 1);
    edge_pass_l2<<<(ET + 3) / 4, 256, 0, stream>>>(
        esrc, edst, h2, as2, ad2, hout, den2, E, N);
    epilogue2<<<((size_t)N * 64 + 255) / 256, 256, 0, stream>>>(
        hout, den2, b2, Ws, bs, scores, N);
}

// Round 2
// 460.747 us; speedup vs baseline: 7.1270x; 7.1270x over previous
//
#include <hip/hip_runtime.h>
#include <hip/hip_bf16.h>
#include <math.h>

// ---------------------------------------------------------------------------
// DualHeadGAT: 2-layer GAT (H1=4,C=64 then H=1,C=64) + linear scoring head.
// N=50000, IN=128, E=800000 (+N self loops). All f32, edge_index int32.
// R2: CSR (group edges by dst) built per-launch; gather-aggregation replaces
// the atomicAdd edge scatter (R1: 3.4 GB atomic WRITE_SIZE, 2850 us).
// Softmax normalization deferred to the per-node epilogue (exact: softmax is
// shift-invariant and |e| <= ~12 so exp() cannot overflow in f32).
// ---------------------------------------------------------------------------

#define LRELU_SLOPE 0.2f

// ---------------- f32 tiled GEMM: C[M,N] = A[M,K] @ B[K,N] -----------------
// 64x64 tile, BK=16, 256 threads, 4x4 micro-tile per thread.
__global__ __launch_bounds__(256)
void gemm64(const float* __restrict__ A, const float* __restrict__ B,
            float* __restrict__ C, int M, int N, int K)
{
    __shared__ float As[16][65];   // A^T tile (k-major), +1 pad
    __shared__ float Bs[16][64];
    const int tid = threadIdx.x;
    const int tx = tid & 15, ty = tid >> 4;
    const int m0 = blockIdx.x * 64, n0 = blockIdx.y * 64;
    float acc[4][4] = {};

    for (int kk = 0; kk < K; kk += 16) {
        {   // A tile: 64 rows x 16 k
            int r = tid >> 2;             // 0..63
            int c = (tid & 3) << 2;       // 0,4,8,12
            int gr = m0 + r;
            float4 v = make_float4(0.f, 0.f, 0.f, 0.f);
            if (gr < M) v = *(const float4*)(A + (size_t)gr * K + kk + c);
            As[c + 0][r] = v.x; As[c + 1][r] = v.y;
            As[c + 2][r] = v.z; As[c + 3][r] = v.w;
        }
        {   // B tile: 16 k x 64 cols
            int r = tid >> 4;             // 0..15
            int c = (tid & 15) << 2;      // 0..60
            float4 v = *(const float4*)(B + (size_t)(kk + r) * N + n0 + c);
            Bs[r][c + 0] = v.x; Bs[r][c + 1] = v.y;
            Bs[r][c + 2] = v.z; Bs[r][c + 3] = v.w;
        }
        __syncthreads();
        #pragma unroll
        for (int k = 0; k < 16; ++k) {
            float a[4], b[4];
            #pragma unroll
            for (int i = 0; i < 4; ++i) a[i] = As[k][ty + 16 * i];
            #pragma unroll
            for (int j = 0; j < 4; ++j) b[j] = Bs[k][tx + 16 * j];
            #pragma unroll
            for (int i = 0; i < 4; ++i)
                #pragma unroll
                for (int j = 0; j < 4; ++j)
                    acc[i][j] = fmaf(a[i], b[j], acc[i][j]);
        }
        __syncthreads();
    }
    #pragma unroll
    for (int i = 0; i < 4; ++i) {
        int m = m0 + ty + 16 * i;
        if (m >= M) continue;
        #pragma unroll
        for (int j = 0; j < 4; ++j)
            C[(size_t)m * N + n0 + tx + 16 * j] = acc[i][j];
    }
}

// ---------------- attention dots: a_src/a_dst [N,H], C=64 ------------------
__global__ __launch_bounds__(256)
void att_dots(const float* __restrict__ h, const float* __restrict__ atts,
              const float* __restrict__ attd, float* __restrict__ as_,
              float* __restrict__ ad_, int rows /*N*H*/, int H)
{
    int w = (blockIdx.x * blockDim.x + threadIdx.x) >> 6;
    int lane = threadIdx.x & 63;
    if (w >= rows) return;
    int hh = w & (H - 1);                      // H is 1 or 4 (pow2)
    float v = h[(size_t)w * 64 + lane];
    float s = v * atts[hh * 64 + lane];
    float d = v * attd[hh * 64 + lane];
    #pragma unroll
    for (int off = 32; off; off >>= 1) {
        s += __shfl_down(s, off);
        d += __shfl_down(d, off);
    }
    if (lane == 0) { as_[w] = s; ad_[w] = d; }
}

// ---------------- CSR build ------------------------------------------------
__global__ __launch_bounds__(256)
void init_deg(int* __restrict__ deg, int N)
{
    int i = blockIdx.x * blockDim.x + threadIdx.x;
    if (i < N) deg[i] = 1;                       // self-loop
}

__global__ __launch_bounds__(256)
void degree_hist(const int* __restrict__ edst, int* __restrict__ deg, int E)
{
    int i = blockIdx.x * blockDim.x + threadIdx.x;
    if (i < E) atomicAdd(&deg[edst[i]], 1);
}

// single-block exclusive scan over N (=50000) elements, 1024 threads
__global__ __launch_bounds__(1024)
void scan_rowptr(const int* __restrict__ deg, int* __restrict__ rowptr, int N)
{
    __shared__ int wsums[16];
    __shared__ int s_carry;
    const int tid = threadIdx.x, lane = tid & 63, wid = tid >> 6;
    if (tid == 0) s_carry = 0;
    __syncthreads();
    for (int base = 0; base < N; base += 1024) {
        int i = base + tid;
        int v = (i < N) ? deg[i] : 0;
        int sc = v;                               // inclusive wave scan
        #pragma unroll
        for (int off = 1; off < 64; off <<= 1) {
            int t = __shfl_up(sc, off);
            if (lane >= off) sc += t;
        }
        if (lane == 63) wsums[wid] = sc;
        __syncthreads();
        if (wid == 0) {
            int wv = (lane < 16) ? wsums[lane] : 0;
            #pragma unroll
            for (int off = 1; off < 16; off <<= 1) {
                int t = __shfl_up(wv, off);
                if (lane >= off) wv += t;
            }
            if (lane < 16) wsums[lane] = wv;      // inclusive wave-sum scan
        }
        __syncthreads();
        int wbase = (wid > 0) ? wsums[wid - 1] : 0;
        if (i < N) rowptr[i] = s_carry + wbase + sc - v;   // exclusive
        __syncthreads();
        if (tid == 1023) s_carry += wsums[15];
        __syncthreads();
    }
    if (threadIdx.x == 0) rowptr[N] = s_carry;
}

__global__ __launch_bounds__(256)
void scatter_edges(const int* __restrict__ esrc, const int* __restrict__ edst,
                   const int* __restrict__ rowptr, int* __restrict__ cursor,
                   int* __restrict__ csr_src, int E, int N)
{
    int i = blockIdx.x * blockDim.x + threadIdx.x;
    int s, d;
    if (i < E)          { s = esrc[i]; d = edst[i]; }
    else if (i < E + N) { s = d = i - E; }
    else return;
    int pos = rowptr[d] + atomicAdd(&cursor[d], 1);
    csr_src[pos] = s;
}

// -------- layer-1 aggregation: one wave per dst node, fused epilogue -------
// out[w, c] = elu( (sum_e p_e * h1[src_e, c]) / (sum_e p_e) + b1[c] )
__global__ __launch_bounds__(256)
void aggregate_l1(const int* __restrict__ rowptr, const int* __restrict__ csr_src,
                  const float* __restrict__ h1, const float* __restrict__ as_,
                  const float* __restrict__ ad_, const float* __restrict__ bias,
                  float* __restrict__ out, int N)
{
    int w = (blockIdx.x * blockDim.x + threadIdx.x) >> 6;
    int lane = threadIdx.x & 63;
    if (w >= N) return;
    const int head = lane >> 4;          // 4 heads x 16 lanes
    const int c0 = lane << 2;            // float4 per lane
    const float ad = ad_[w * 4 + head];
    int e = rowptr[w];
    const int e1 = rowptr[w + 1];
    float4 acc = make_float4(0.f, 0.f, 0.f, 0.f);
    float dsum = 0.f;
    for (; e + 1 < e1; e += 2) {         // 2x unroll for ILP
        int s0 = csr_src[e], s1 = csr_src[e + 1];
        float el0 = as_[s0 * 4 + head] + ad;
        float el1 = as_[s1 * 4 + head] + ad;
        el0 = el0 > 0.f ? el0 : LRELU_SLOPE * el0;
        el1 = el1 > 0.f ? el1 : LRELU_SLOPE * el1;
        float p0 = __expf(el0), p1 = __expf(el1);
        float4 v0 = *(const float4*)(h1 + (size_t)s0 * 256 + c0);
        float4 v1 = *(const float4*)(h1 + (size_t)s1 * 256 + c0);
        acc.x = fmaf(p0, v0.x, acc.x); acc.y = fmaf(p0, v0.y, acc.y);
        acc.z = fmaf(p0, v0.z, acc.z); acc.w = fmaf(p0, v0.w, acc.w);
        acc.x = fmaf(p1, v1.x, acc.x); acc.y = fmaf(p1, v1.y, acc.y);
        acc.z = fmaf(p1, v1.z, acc.z); acc.w = fmaf(p1, v1.w, acc.w);
        dsum += p0 + p1;
    }
    if (e < e1) {
        int s0 = csr_src[e];
        float el0 = as_[s0 * 4 + head] + ad;
        el0 = el0 > 0.f ? el0 : LRELU_SLOPE * el0;
        float p0 = __expf(el0);
        float4 v0 = *(const float4*)(h1 + (size_t)s0 * 256 + c0);
        acc.x = fmaf(p0, v0.x, acc.x); acc.y = fmaf(p0, v0.y, acc.y);
        acc.z = fmaf(p0, v0.z, acc.z); acc.w = fmaf(p0, v0.w, acc.w);
        dsum += p0;
    }
    const float inv = 1.f / (dsum + 1e-16f);
    const float4 b = *(const float4*)(bias + c0);
    float4 o;
    o.x = acc.x * inv + b.x; o.x = o.x > 0.f ? o.x : expm1f(o.x);
    o.y = acc.y * inv + b.y; o.y = o.y > 0.f ? o.y : expm1f(o.y);
    o.z = acc.z * inv + b.z; o.z = o.z > 0.f ? o.z : expm1f(o.z);
    o.w = acc.w * inv + b.w; o.w = o.w > 0.f ? o.w : expm1f(o.w);
    *(float4*)(out + (size_t)w * 256 + c0) = o;
}

// -------- layer-2 aggregation + scoring head, one wave per dst node --------
__global__ __launch_bounds__(256)
void aggregate_l2(const int* __restrict__ rowptr, const int* __restrict__ csr_src,
                  const float* __restrict__ h2, const float* __restrict__ as_,
                  const float* __restrict__ ad_, const float* __restrict__ b2,
                  const float* __restrict__ Wsv, const float* __restrict__ bs,
                  float* __restrict__ hout, float* __restrict__ scores, int N)
{
    int w = (blockIdx.x * blockDim.x + threadIdx.x) >> 6;
    int lane = threadIdx.x & 63;
    if (w >= N) return;
    const float ad = ad_[w];
    int e = rowptr[w];
    const int e1 = rowptr[w + 1];
    float acc = 0.f, dsum = 0.f;
    for (; e + 1 < e1; e += 2) {
        int s0 = csr_src[e], s1 = csr_src[e + 1];
        float el0 = as_[s0] + ad;
        float el1 = as_[s1] + ad;
        el0 = el0 > 0.f ? el0 : LRELU_SLOPE * el0;
        el1 = el1 > 0.f ? el1 : LRELU_SLOPE * el1;
        float p0 = __expf(el0), p1 = __expf(el1);
        acc = fmaf(p0, h2[(size_t)s0 * 64 + lane], acc);
        acc = fmaf(p1, h2[(size_t)s1 * 64 + lane], acc);
        dsum += p0 + p1;
    }
    if (e < e1) {
        int s0 = csr_src[e];
        float el0 = as_[s0] + ad;
        el0 = el0 > 0.f ? el0 : LRELU_SLOPE * el0;
        float p0 = __expf(el0);
        acc = fmaf(p0, h2[(size_t)s0 * 64 + lane], acc);
        dsum += p0;
    }
    float v = acc / (dsum + 1e-16f) + b2[lane];
    v = v > 0.f ? v : expm1f(v);
    hout[(size_t)w * 64 + lane] = v;
    float sc = v * Wsv[lane];
    #pragma unroll
    for (int off = 32; off; off >>= 1) sc += __shfl_down(sc, off);
    if (lane == 0) scores[w] = sc + bs[0];
}

// ---------------------------------------------------------------------------
extern "C" void kernel_launch(void* const* d_in, const int* in_sizes, int n_in,
                              void* d_out, int out_size, void* d_ws, size_t ws_size,
                              hipStream_t stream)
{
    const float* x    = (const float*)d_in[0];
    const int*   ei   = (const int*)d_in[1];
    const float* W1   = (const float*)d_in[2];
    const float* as1w = (const float*)d_in[3];
    const float* ad1w = (const float*)d_in[4];
    const float* b1   = (const float*)d_in[5];
    const float* W2   = (const float*)d_in[6];
    const float* as2w = (const float*)d_in[7];
    const float* ad2w = (const float*)d_in[8];
    const float* b2   = (const float*)d_in[9];
    const float* Ws   = (const float*)d_in[10];
    const float* bs   = (const float*)d_in[11];

    const int N  = in_sizes[0] / 128;   // 50000
    const int E  = in_sizes[1] / 2;     // 800000
    const int ET = E + N;
    const int* esrc = ei;
    const int* edst = ei + E;

    // workspace layout
    float* ws   = (float*)d_ws;
    float* h1   = ws;                              // N*256
    float* hl1  = h1  + (size_t)N * 256;           // N*256 (layer-1 output)
    float* as1  = hl1 + (size_t)N * 256;           // N*4
    float* ad1  = as1 + (size_t)N * 4;             // N*4
    int*   deg    = (int*)(ad1 + (size_t)N * 4);   // N
    int*   cursor = deg + N;                       // N
    int*   rowptr = cursor + N;                    // N+1
    int*   csr_src= rowptr + N + 1;                // ET
    // layer-2 temporaries reuse h1's region (h1 dead after aggregate_l1)
    float* h2   = h1;                              // N*64
    float* as2  = h2 + (size_t)N * 64;             // N
    float* ad2  = as2 + N;                         // N

    float* hout   = (float*)d_out;                 // N*64
    float* scores = hout + (size_t)N * 64;         // N

    // ---------------- CSR build (shared by both layers) ----------------
    init_deg<<<(N + 255) / 256, 256, 0, stream>>>(deg, N);
    degree_hist<<<(E + 255) / 256, 256, 0, stream>>>(edst, deg, E);
    scan_rowptr<<<1, 1024, 0, stream>>>(deg, rowptr, N);
    hipMemsetAsync(cursor, 0, (size_t)N * sizeof(int), stream);
    scatter_edges<<<(ET + 255) / 256, 256, 0, stream>>>(
        esrc, edst, rowptr, cursor, csr_src, E, N);

    // ---------------- layer 1 ----------------
    {
        dim3 grid((N + 63) / 64, 256 / 64);
        gemm64<<<grid, 256, 0, stream>>>(x, W1, h1, N, 256, 128);
    }
    att_dots<<<((size_t)N * 4 * 64 + 255) / 256, 256, 0, stream>>>(
        h1, as1w, ad1w, as1, ad1, N * 4, 4);
    aggregate_l1<<<((size_t)N * 64 + 255) / 256, 256, 0, stream>>>(
        rowptr, csr_src, h1, as1, ad1, b1, hl1, N);

    // ---------------- layer 2 ----------------
    {
        dim3 grid((N + 63) / 64, 1);
        gemm64<<<grid, 256, 0, stream>>>(hl1, W2, h2, N, 64, 256);
    }
    att_dots<<<((size_t)N * 64 + 255) / 256, 256, 0, stream>>>(
        h2, as2w, ad2w, as2, ad2, N, 1);
    aggregate_l2<<<((size_t)N * 64 + 255) / 256, 256, 0, stream>>>(
        rowptr, csr_src, h2, as2, ad2, b2, Ws, bs, hout, scores, N);
}

// Round 3
// 331.200 us; speedup vs baseline: 9.9147x; 1.3911x over previous
//
#include <hip/hip_runtime.h>
#include <hip/hip_bf16.h>
#include <math.h>

// ---------------------------------------------------------------------------
// DualHeadGAT R3: bf16 MFMA GEMMs (LDS-free, pre-fragmented B), fused
// attention dots in GEMM epilogue, CSR gather aggregation (R2), deferred
// softmax normalization (exact).
// N=50000, IN=128, E=800000 (+N self loops). f32 in/out, int32 edges.
// ---------------------------------------------------------------------------

#define LRELU_SLOPE 0.2f

typedef __attribute__((ext_vector_type(8))) short short8;   // 8 bf16 = 4 VGPR
typedef __attribute__((ext_vector_type(4))) float f32x4;

__device__ inline ushort f2bf(float f) {            // RNE f32 -> bf16
    uint u = __float_as_uint(f);
    return (ushort)((u + 0x7FFFu + ((u >> 16) & 1u)) >> 16);
}

// ---------------- x (f32) -> bf16, 4 elems/thread --------------------------
__global__ __launch_bounds__(256)
void conv_bf16(const float* __restrict__ in, ushort* __restrict__ out, int n)
{
    int i = (blockIdx.x * blockDim.x + threadIdx.x) << 2;
    if (i >= n) return;
    float4 v = *(const float4*)(in + i);
    ushort4 o;
    o.x = f2bf(v.x); o.y = f2bf(v.y); o.z = f2bf(v.z); o.w = f2bf(v.w);
    *(ushort4*)(out + i) = o;
}

// ------- pre-fragment W[K][16J] (f32, row-major) into MFMA B-frag order ----
// out[((j*T + t)*64 + l)*8 + b] = bf16( W[(t*32 + (l>>4)*8 + b) * ldn + j*16 + (l&15)] )
__global__ __launch_bounds__(256)
void prefrag(const float* __restrict__ W, ushort* __restrict__ out,
             int J, int T, int ldn)
{
    int tid = blockIdx.x * blockDim.x + threadIdx.x;
    if (tid >= J * T * 64) return;
    int l = tid & 63, jt = tid >> 6;
    int t = jt % T, j = jt / T;
    int n = j * 16 + (l & 15);
    int k0 = t * 32 + (l >> 4) * 8;
    ushort o[8];
    #pragma unroll
    for (int b = 0; b < 8; ++b) o[b] = f2bf(W[(size_t)(k0 + b) * ldn + n]);
    *(short8*)(out + (size_t)tid * 8) = *(short8*)o;
}

// ---------------- MFMA GEMM, row-panel, LDS-free ---------------------------
// C[M,16J] = A[M,32T] @ B ; one wave per 16 rows; fused att dots -> as_/ad_.
template<int J, int T, int H>
__global__ __launch_bounds__(256)
void gemm_mfma(const ushort* __restrict__ A, const ushort* __restrict__ Bf,
               float* __restrict__ C, const float* __restrict__ attS,
               const float* __restrict__ attD, float* __restrict__ as_,
               float* __restrict__ ad_, int M)
{
    constexpr int K = 32 * T;
    constexpr int NN = 16 * J;
    const int l = threadIdx.x & 63;
    const int wid = blockIdx.x * (blockDim.x >> 6) + (threadIdx.x >> 6);
    const int base = wid * 16;
    if (base >= M) return;
    const int lm = l & 15, lg = l >> 4;

    short8 a[T];
    const ushort* ap = A + (size_t)(base + lm) * K + lg * 8;
    #pragma unroll
    for (int t = 0; t < T; ++t) a[t] = *(const short8*)(ap + t * 32);

    f32x4 acc[J];
    #pragma unroll
    for (int j = 0; j < J; ++j) acc[j] = (f32x4){0.f, 0.f, 0.f, 0.f};

    const ushort* bp = Bf + (size_t)l * 8;
    #pragma unroll
    for (int j = 0; j < J; ++j)
        #pragma unroll
        for (int t = 0; t < T; ++t) {
            short8 b = *(const short8*)(bp + (size_t)(j * T + t) * 512);
            acc[j] = __builtin_amdgcn_mfma_f32_16x16x32_bf16(a[t], b, acc[j], 0, 0, 0);
        }

    // epilogue: store C (f32) + fused attention dots
    float sp[H][4], dp[H][4];
    #pragma unroll
    for (int h = 0; h < H; ++h)
        #pragma unroll
        for (int r = 0; r < 4; ++r) { sp[h][r] = 0.f; dp[h][r] = 0.f; }

    #pragma unroll
    for (int j = 0; j < J; ++j) {
        const int h = j / (J / H);
        const int coff = (j % (J / H)) * 16 + lm;     // col within head (0..63)
        float ws = attS[h * 64 + coff];
        float wd = attD[h * 64 + coff];
        #pragma unroll
        for (int r = 0; r < 4; ++r) {
            int row = base + lg * 4 + r;
            C[(size_t)row * NN + j * 16 + lm] = acc[j][r];
            sp[h][r] = fmaf(acc[j][r], ws, sp[h][r]);
            dp[h][r] = fmaf(acc[j][r], wd, dp[h][r]);
        }
    }
    #pragma unroll
    for (int h = 0; h < H; ++h)
        #pragma unroll
        for (int r = 0; r < 4; ++r) {
            float s = sp[h][r], d = dp[h][r];
            s += __shfl_xor(s, 1); d += __shfl_xor(d, 1);
            s += __shfl_xor(s, 2); d += __shfl_xor(d, 2);
            s += __shfl_xor(s, 4); d += __shfl_xor(d, 4);
            s += __shfl_xor(s, 8); d += __shfl_xor(d, 8);
            if (lm == 0) {
                int row = base + lg * 4 + r;
                as_[row * H + h] = s;
                ad_[row * H + h] = d;
            }
        }
}

// ---------------- CSR build ------------------------------------------------
__global__ __launch_bounds__(256)
void init_deg(int* __restrict__ deg, int N)
{
    int i = blockIdx.x * blockDim.x + threadIdx.x;
    if (i < N) deg[i] = 1;                       // self-loop
}

__global__ __launch_bounds__(256)
void degree_hist(const int* __restrict__ edst, int* __restrict__ deg, int E)
{
    int i = blockIdx.x * blockDim.x + threadIdx.x;
    if (i < E) atomicAdd(&deg[edst[i]], 1);
}

// single-block exclusive scan, 4 elems/thread (N % 4 == 0)
__global__ __launch_bounds__(1024)
void scan_rowptr(const int* __restrict__ deg, int* __restrict__ rowptr, int N)
{
    __shared__ int wsums[16];
    __shared__ int s_carry;
    const int tid = threadIdx.x, lane = tid & 63, wid = tid >> 6;
    if (tid == 0) s_carry = 0;
    __syncthreads();
    const int N4 = N >> 2;
    for (int base = 0; base < N4; base += 1024) {
        int i4 = base + tid;
        int4 v = (i4 < N4) ? ((const int4*)deg)[i4] : make_int4(0, 0, 0, 0);
        int tsum = v.x + v.y + v.z + v.w;
        int sc = tsum;
        #pragma unroll
        for (int off = 1; off < 64; off <<= 1) {
            int t = __shfl_up(sc, off);
            if (lane >= off) sc += t;
        }
        if (lane == 63) wsums[wid] = sc;
        __syncthreads();
        if (wid == 0) {
            int wv = (lane < 16) ? wsums[lane] : 0;
            #pragma unroll
            for (int off = 1; off < 16; off <<= 1) {
                int t = __shfl_up(wv, off);
                if (lane >= off) wv += t;
            }
            if (lane < 16) wsums[lane] = wv;
        }
        __syncthreads();
        int wbase = (wid > 0) ? wsums[wid - 1] : 0;
        int excl = s_carry + wbase + sc - tsum;
        if (i4 < N4) {
            int4 o;
            o.x = excl; o.y = excl + v.x; o.z = o.y + v.y; o.w = o.z + v.z;
            ((int4*)rowptr)[i4] = o;
        }
        __syncthreads();
        if (tid == 0) s_carry += wsums[15];
        __syncthreads();
    }
    if (tid == 0) rowptr[N] = s_carry;
}

__global__ __launch_bounds__(256)
void scatter_edges(const int* __restrict__ esrc, const int* __restrict__ edst,
                   const int* __restrict__ rowptr, int* __restrict__ cursor,
                   int* __restrict__ csr_src, int E, int N)
{
    int i = blockIdx.x * blockDim.x + threadIdx.x;
    int s, d;
    if (i < E)          { s = esrc[i]; d = edst[i]; }
    else if (i < E + N) { s = d = i - E; }
    else return;
    int pos = rowptr[d] + atomicAdd(&cursor[d], 1);
    csr_src[pos] = s;
}

// -------- layer-1 aggregation: wave per dst node; writes bf16 hl1 ----------
__global__ __launch_bounds__(256)
void aggregate_l1(const int* __restrict__ rowptr, const int* __restrict__ csr_src,
                  const float* __restrict__ h1, const float* __restrict__ as_,
                  const float* __restrict__ ad_, const float* __restrict__ bias,
                  ushort* __restrict__ outbf, int N)
{
    int w = (blockIdx.x * blockDim.x + threadIdx.x) >> 6;
    int lane = threadIdx.x & 63;
    if (w >= N) return;
    const int head = lane >> 4;          // 4 heads x 16 lanes
    const int c0 = lane << 2;            // float4 per lane
    const float ad = ad_[w * 4 + head];
    int e = rowptr[w];
    const int e1 = rowptr[w + 1];
    float4 acc = make_float4(0.f, 0.f, 0.f, 0.f);
    float dsum = 0.f;
    for (; e + 1 < e1; e += 2) {
        int s0 = csr_src[e], s1 = csr_src[e + 1];
        float el0 = as_[s0 * 4 + head] + ad;
        float el1 = as_[s1 * 4 + head] + ad;
        el0 = el0 > 0.f ? el0 : LRELU_SLOPE * el0;
        el1 = el1 > 0.f ? el1 : LRELU_SLOPE * el1;
        float p0 = __expf(el0), p1 = __expf(el1);
        float4 v0 = *(const float4*)(h1 + (size_t)s0 * 256 + c0);
        float4 v1 = *(const float4*)(h1 + (size_t)s1 * 256 + c0);
        acc.x = fmaf(p0, v0.x, acc.x); acc.y = fmaf(p0, v0.y, acc.y);
        acc.z = fmaf(p0, v0.z, acc.z); acc.w = fmaf(p0, v0.w, acc.w);
        acc.x = fmaf(p1, v1.x, acc.x); acc.y = fmaf(p1, v1.y, acc.y);
        acc.z = fmaf(p1, v1.z, acc.z); acc.w = fmaf(p1, v1.w, acc.w);
        dsum += p0 + p1;
    }
    if (e < e1) {
        int s0 = csr_src[e];
        float el0 = as_[s0 * 4 + head] + ad;
        el0 = el0 > 0.f ? el0 : LRELU_SLOPE * el0;
        float p0 = __expf(el0);
        float4 v0 = *(const float4*)(h1 + (size_t)s0 * 256 + c0);
        acc.x = fmaf(p0, v0.x, acc.x); acc.y = fmaf(p0, v0.y, acc.y);
        acc.z = fmaf(p0, v0.z, acc.z); acc.w = fmaf(p0, v0.w, acc.w);
        dsum += p0;
    }
    const float inv = 1.f / (dsum + 1e-16f);
    const float4 b = *(const float4*)(bias + c0);
    float ox = acc.x * inv + b.x; ox = ox > 0.f ? ox : expm1f(ox);
    float oy = acc.y * inv + b.y; oy = oy > 0.f ? oy : expm1f(oy);
    float oz = acc.z * inv + b.z; oz = oz > 0.f ? oz : expm1f(oz);
    float ow = acc.w * inv + b.w; ow = ow > 0.f ? ow : expm1f(ow);
    ushort4 o;
    o.x = f2bf(ox); o.y = f2bf(oy); o.z = f2bf(oz); o.w = f2bf(ow);
    *(ushort4*)(outbf + (size_t)w * 256 + c0) = o;
}

// -------- layer-2 aggregation + scoring head, one wave per dst node --------
__global__ __launch_bounds__(256)
void aggregate_l2(const int* __restrict__ rowptr, const int* __restrict__ csr_src,
                  const float* __restrict__ h2, const float* __restrict__ as_,
                  const float* __restrict__ ad_, const float* __restrict__ b2,
                  const float* __restrict__ Wsv, const float* __restrict__ bs,
                  float* __restrict__ hout, float* __restrict__ scores, int N)
{
    int w = (blockIdx.x * blockDim.x + threadIdx.x) >> 6;
    int lane = threadIdx.x & 63;
    if (w >= N) return;
    const float ad = ad_[w];
    int e = rowptr[w];
    const int e1 = rowptr[w + 1];
    float acc = 0.f, dsum = 0.f;
    for (; e + 1 < e1; e += 2) {
        int s0 = csr_src[e], s1 = csr_src[e + 1];
        float el0 = as_[s0] + ad;
        float el1 = as_[s1] + ad;
        el0 = el0 > 0.f ? el0 : LRELU_SLOPE * el0;
        el1 = el1 > 0.f ? el1 : LRELU_SLOPE * el1;
        float p0 = __expf(el0), p1 = __expf(el1);
        acc = fmaf(p0, h2[(size_t)s0 * 64 + lane], acc);
        acc = fmaf(p1, h2[(size_t)s1 * 64 + lane], acc);
        dsum += p0 + p1;
    }
    if (e < e1) {
        int s0 = csr_src[e];
        float el0 = as_[s0] + ad;
        el0 = el0 > 0.f ? el0 : LRELU_SLOPE * el0;
        float p0 = __expf(el0);
        acc = fmaf(p0, h2[(size_t)s0 * 64 + lane], acc);
        dsum += p0;
    }
    float v = acc / (dsum + 1e-16f) + b2[lane];
    v = v > 0.f ? v : expm1f(v);
    hout[(size_t)w * 64 + lane] = v;
    float sc = v * Wsv[lane];
    #pragma unroll
    for (int off = 32; off; off >>= 1) sc += __shfl_down(sc, off);
    if (lane == 0) scores[w] = sc + bs[0];
}

// ---------------------------------------------------------------------------
extern "C" void kernel_launch(void* const* d_in, const int* in_sizes, int n_in,
                              void* d_out, int out_size, void* d_ws, size_t ws_size,
                              hipStream_t stream)
{
    const float* x    = (const float*)d_in[0];
    const int*   ei   = (const int*)d_in[1];
    const float* W1   = (const float*)d_in[2];
    const float* as1w = (const float*)d_in[3];
    const float* ad1w = (const float*)d_in[4];
    const float* b1   = (const float*)d_in[5];
    const float* W2   = (const float*)d_in[6];
    const float* as2w = (const float*)d_in[7];
    const float* ad2w = (const float*)d_in[8];
    const float* b2   = (const float*)d_in[9];
    const float* Ws   = (const float*)d_in[10];
    const float* bs   = (const float*)d_in[11];

    const int N  = in_sizes[0] / 128;   // 50000
    const int E  = in_sizes[1] / 2;     // 800000
    const int ET = E + N;
    const int* esrc = ei;
    const int* edst = ei + E;

    // ---- workspace layout (all chunks 16B-aligned) ----
    float*  h1    = (float*)d_ws;                        // N*256 f32
    ushort* hl1bf = (ushort*)(h1 + (size_t)N * 256);     // N*256 bf16
    ushort* xbf   = hl1bf + (size_t)N * 256;             // N*128 bf16
    ushort* bfr1  = xbf + (size_t)N * 128;               // 16*4*64*8 = 32768
    ushort* bfr2  = bfr1 + 32768;                        // 4*8*64*8  = 16384
    float*  h2    = (float*)(bfr2 + 16384);              // N*64 f32
    float*  as1   = h2 + (size_t)N * 64;                 // N*4
    float*  ad1   = as1 + (size_t)N * 4;                 // N*4
    float*  as2   = ad1 + (size_t)N * 4;                 // N
    float*  ad2   = as2 + N;                             // N
    int*    deg    = (int*)(ad2 + N);                    // N
    int*    cursor = deg + N;                            // N
    int*    rowptr = cursor + N;                         // N+1
    int*    csr_src= rowptr + N + 1;                     // ET

    float* hout   = (float*)d_out;                       // N*64
    float* scores = hout + (size_t)N * 64;               // N

    // ---------------- CSR build (shared by both layers) ----------------
    init_deg<<<(N + 255) / 256, 256, 0, stream>>>(deg, N);
    degree_hist<<<(E + 255) / 256, 256, 0, stream>>>(edst, deg, E);
    scan_rowptr<<<1, 1024, 0, stream>>>(deg, rowptr, N);
    hipMemsetAsync(cursor, 0, (size_t)N * sizeof(int), stream);
    scatter_edges<<<(ET + 255) / 256, 256, 0, stream>>>(
        esrc, edst, rowptr, cursor, csr_src, E, N);

    // ---------------- input conversion / weight pre-fragmentation -------
    conv_bf16<<<((size_t)N * 128 / 4 + 255) / 256, 256, 0, stream>>>(
        x, xbf, N * 128);
    prefrag<<<(16 * 4 * 64 + 255) / 256, 256, 0, stream>>>(W1, bfr1, 16, 4, 256);
    prefrag<<<(4 * 8 * 64 + 255) / 256, 256, 0, stream>>>(W2, bfr2, 4, 8, 64);

    // ---------------- layer 1 ----------------
    gemm_mfma<16, 4, 4><<<(N / 16 + 3) / 4, 256, 0, stream>>>(
        xbf, bfr1, h1, as1w, ad1w, as1, ad1, N);
    aggregate_l1<<<((size_t)N * 64 + 255) / 256, 256, 0, stream>>>(
        rowptr, csr_src, h1, as1, ad1, b1, hl1bf, N);

    // ---------------- layer 2 ----------------
    gemm_mfma<4, 8, 1><<<(N / 16 + 3) / 4, 256, 0, stream>>>(
        hl1bf, bfr2, h2, as2w, ad2w, as2, ad2, N);
    aggregate_l2<<<((size_t)N * 64 + 255) / 256, 256, 0, stream>>>(
        rowptr, csr_src, h2, as2, ad2, b2, Ws, bs, hout, scores, N);
}

// Round 4
// 256.501 us; speedup vs baseline: 12.8021x; 1.2912x over previous
//
#include <hip/hip_runtime.h>
#include <hip/hip_bf16.h>
#include <math.h>

// ---------------------------------------------------------------------------
// DualHeadGAT R4: bf16 feature gathers (h1/h2 stored bf16 straight from the
// MFMA GEMM epilogue), CSR gather aggregation with 4x edge unroll, implicit
// self-loops (no extra CSR entries), deferred softmax normalization (exact).
// N=50000, IN=128, E=800000. f32 in/out, int32 edges.
// ---------------------------------------------------------------------------

#define LRELU_SLOPE 0.2f

typedef __attribute__((ext_vector_type(8))) short short8;   // 8 bf16 = 4 VGPR
typedef __attribute__((ext_vector_type(4))) float f32x4;

__device__ inline ushort f2bf(float f) {            // RNE f32 -> bf16
    uint u = __float_as_uint(f);
    return (ushort)((u + 0x7FFFu + ((u >> 16) & 1u)) >> 16);
}
__device__ inline float bf2f(ushort u) {
    return __uint_as_float(((uint)u) << 16);
}

// ---------------- x (f32) -> bf16, 4 elems/thread --------------------------
__global__ __launch_bounds__(256)
void conv_bf16(const float* __restrict__ in, ushort* __restrict__ out, int n)
{
    int i = (blockIdx.x * blockDim.x + threadIdx.x) << 2;
    if (i >= n) return;
    float4 v = *(const float4*)(in + i);
    ushort4 o;
    o.x = f2bf(v.x); o.y = f2bf(v.y); o.z = f2bf(v.z); o.w = f2bf(v.w);
    *(ushort4*)(out + i) = o;
}

// ------- pre-fragment W[K][16J] (f32, row-major) into MFMA B-frag order ----
__global__ __launch_bounds__(256)
void prefrag(const float* __restrict__ W, ushort* __restrict__ out,
             int J, int T, int ldn)
{
    int tid = blockIdx.x * blockDim.x + threadIdx.x;
    if (tid >= J * T * 64) return;
    int l = tid & 63, jt = tid >> 6;
    int t = jt % T, j = jt / T;
    int n = j * 16 + (l & 15);
    int k0 = t * 32 + (l >> 4) * 8;
    ushort o[8];
    #pragma unroll
    for (int b = 0; b < 8; ++b) o[b] = f2bf(W[(size_t)(k0 + b) * ldn + n]);
    *(short8*)(out + (size_t)tid * 8) = *(short8*)o;
}

// ---------------- MFMA GEMM, row-panel, LDS-free, bf16 output --------------
// Cbf[M,16J] = bf16(A[M,32T] @ B); one wave per 16 rows; fused att dots.
template<int J, int T, int H>
__global__ __launch_bounds__(256)
void gemm_mfma(const ushort* __restrict__ A, const ushort* __restrict__ Bf,
               ushort* __restrict__ Cbf, const float* __restrict__ attS,
               const float* __restrict__ attD, float* __restrict__ as_,
               float* __restrict__ ad_, int M)
{
    constexpr int K = 32 * T;
    constexpr int NN = 16 * J;
    const int l = threadIdx.x & 63;
    const int wid = blockIdx.x * (blockDim.x >> 6) + (threadIdx.x >> 6);
    const int base = wid * 16;
    if (base >= M) return;
    const int lm = l & 15, lg = l >> 4;

    short8 a[T];
    const ushort* ap = A + (size_t)(base + lm) * K + lg * 8;
    #pragma unroll
    for (int t = 0; t < T; ++t) a[t] = *(const short8*)(ap + t * 32);

    f32x4 acc[J];
    #pragma unroll
    for (int j = 0; j < J; ++j) acc[j] = (f32x4){0.f, 0.f, 0.f, 0.f};

    const ushort* bp = Bf + (size_t)l * 8;
    #pragma unroll
    for (int j = 0; j < J; ++j)
        #pragma unroll
        for (int t = 0; t < T; ++t) {
            short8 b = *(const short8*)(bp + (size_t)(j * T + t) * 512);
            acc[j] = __builtin_amdgcn_mfma_f32_16x16x32_bf16(a[t], b, acc[j], 0, 0, 0);
        }

    // epilogue: store bf16 C + fused attention dots (f32 precision)
    float sp[H][4], dp[H][4];
    #pragma unroll
    for (int h = 0; h < H; ++h)
        #pragma unroll
        for (int r = 0; r < 4; ++r) { sp[h][r] = 0.f; dp[h][r] = 0.f; }

    #pragma unroll
    for (int j = 0; j < J; ++j) {
        const int h = j / (J / H);
        const int coff = (j % (J / H)) * 16 + lm;     // col within head
        float ws = attS[h * 64 + coff];
        float wd = attD[h * 64 + coff];
        #pragma unroll
        for (int r = 0; r < 4; ++r) {
            int row = base + lg * 4 + r;
            Cbf[(size_t)row * NN + j * 16 + lm] = f2bf(acc[j][r]);
            sp[h][r] = fmaf(acc[j][r], ws, sp[h][r]);
            dp[h][r] = fmaf(acc[j][r], wd, dp[h][r]);
        }
    }
    #pragma unroll
    for (int h = 0; h < H; ++h)
        #pragma unroll
        for (int r = 0; r < 4; ++r) {
            float s = sp[h][r], d = dp[h][r];
            s += __shfl_xor(s, 1); d += __shfl_xor(d, 1);
            s += __shfl_xor(s, 2); d += __shfl_xor(d, 2);
            s += __shfl_xor(s, 4); d += __shfl_xor(d, 4);
            s += __shfl_xor(s, 8); d += __shfl_xor(d, 8);
            if (lm == 0) {
                int row = base + lg * 4 + r;
                as_[row * H + h] = s;
                ad_[row * H + h] = d;
            }
        }
}

// ---------------- CSR build (real edges only; self-loops implicit) ---------
__global__ __launch_bounds__(256)
void degree_hist(const int* __restrict__ edst, int* __restrict__ deg, int E)
{
    int i = blockIdx.x * blockDim.x + threadIdx.x;
    if (i < E) atomicAdd(&deg[edst[i]], 1);
}

// single-block exclusive scan, 4 elems/thread; also zeroes cursor
__global__ __launch_bounds__(1024)
void scan_rowptr(const int* __restrict__ deg, int* __restrict__ rowptr,
                 int* __restrict__ cursor, int N)
{
    __shared__ int wsums[16];
    __shared__ int s_carry;
    const int tid = threadIdx.x, lane = tid & 63, wid = tid >> 6;
    if (tid == 0) s_carry = 0;
    __syncthreads();
    const int N4 = N >> 2;
    for (int base = 0; base < N4; base += 1024) {
        int i4 = base + tid;
        int4 v = (i4 < N4) ? ((const int4*)deg)[i4] : make_int4(0, 0, 0, 0);
        int tsum = v.x + v.y + v.z + v.w;
        int sc = tsum;
        #pragma unroll
        for (int off = 1; off < 64; off <<= 1) {
            int t = __shfl_up(sc, off);
            if (lane >= off) sc += t;
        }
        if (lane == 63) wsums[wid] = sc;
        __syncthreads();
        if (wid == 0) {
            int wv = (lane < 16) ? wsums[lane] : 0;
            #pragma unroll
            for (int off = 1; off < 16; off <<= 1) {
                int t = __shfl_up(wv, off);
                if (lane >= off) wv += t;
            }
            if (lane < 16) wsums[lane] = wv;
        }
        __syncthreads();
        int wbase = (wid > 0) ? wsums[wid - 1] : 0;
        int excl = s_carry + wbase + sc - tsum;
        if (i4 < N4) {
            int4 o;
            o.x = excl; o.y = excl + v.x; o.z = o.y + v.y; o.w = o.z + v.z;
            ((int4*)rowptr)[i4] = o;
            ((int4*)cursor)[i4] = make_int4(0, 0, 0, 0);
        }
        __syncthreads();
        if (tid == 0) s_carry += wsums[15];
        __syncthreads();
    }
    if (tid == 0) rowptr[N] = s_carry;
}

__global__ __launch_bounds__(256)
void scatter_edges(const int* __restrict__ esrc, const int* __restrict__ edst,
                   const int* __restrict__ rowptr, int* __restrict__ cursor,
                   int* __restrict__ csr_src, int E)
{
    int i = blockIdx.x * blockDim.x + threadIdx.x;
    if (i >= E) return;
    int s = esrc[i], d = edst[i];
    int pos = rowptr[d] + atomicAdd(&cursor[d], 1);
    csr_src[pos] = s;
}

// -------- layer-1 aggregation: wave per dst node; bf16 gather --------------
__global__ __launch_bounds__(256)
void aggregate_l1(const int* __restrict__ rowptr, const int* __restrict__ csr_src,
                  const ushort* __restrict__ h1, const float* __restrict__ as_,
                  const float* __restrict__ ad_, const float* __restrict__ bias,
                  ushort* __restrict__ outbf, int N)
{
    int w = (blockIdx.x * blockDim.x + threadIdx.x) >> 6;
    int lane = threadIdx.x & 63;
    if (w >= N) return;
    const int head = lane >> 4;          // 4 heads x 16 lanes
    const int c0 = lane << 2;            // ushort4 per lane
    const float ad = ad_[w * 4 + head];
    float4 acc = make_float4(0.f, 0.f, 0.f, 0.f);
    float dsum = 0.f;

    // implicit self-loop
    {
        float el = as_[w * 4 + head] + ad;
        el = el > 0.f ? el : LRELU_SLOPE * el;
        float p = __expf(el);
        ushort4 u = *(const ushort4*)(h1 + (size_t)w * 256 + c0);
        acc.x = p * bf2f(u.x); acc.y = p * bf2f(u.y);
        acc.z = p * bf2f(u.z); acc.w = p * bf2f(u.w);
        dsum = p;
    }

    int e = rowptr[w];
    const int e1 = rowptr[w + 1];
    for (; e + 3 < e1; e += 4) {         // 4x unroll for MLP
        int s0 = csr_src[e], s1 = csr_src[e + 1];
        int s2 = csr_src[e + 2], s3 = csr_src[e + 3];
        float e0 = as_[s0 * 4 + head] + ad, e1v = as_[s1 * 4 + head] + ad;
        float e2 = as_[s2 * 4 + head] + ad, e3 = as_[s3 * 4 + head] + ad;
        e0 = e0 > 0.f ? e0 : LRELU_SLOPE * e0;
        e1v = e1v > 0.f ? e1v : LRELU_SLOPE * e1v;
        e2 = e2 > 0.f ? e2 : LRELU_SLOPE * e2;
        e3 = e3 > 0.f ? e3 : LRELU_SLOPE * e3;
        float p0 = __expf(e0), p1 = __expf(e1v);
        float p2 = __expf(e2), p3 = __expf(e3);
        ushort4 u0 = *(const ushort4*)(h1 + (size_t)s0 * 256 + c0);
        ushort4 u1 = *(const ushort4*)(h1 + (size_t)s1 * 256 + c0);
        ushort4 u2 = *(const ushort4*)(h1 + (size_t)s2 * 256 + c0);
        ushort4 u3 = *(const ushort4*)(h1 + (size_t)s3 * 256 + c0);
        acc.x = fmaf(p0, bf2f(u0.x), acc.x); acc.y = fmaf(p0, bf2f(u0.y), acc.y);
        acc.z = fmaf(p0, bf2f(u0.z), acc.z); acc.w = fmaf(p0, bf2f(u0.w), acc.w);
        acc.x = fmaf(p1, bf2f(u1.x), acc.x); acc.y = fmaf(p1, bf2f(u1.y), acc.y);
        acc.z = fmaf(p1, bf2f(u1.z), acc.z); acc.w = fmaf(p1, bf2f(u1.w), acc.w);
        acc.x = fmaf(p2, bf2f(u2.x), acc.x); acc.y = fmaf(p2, bf2f(u2.y), acc.y);
        acc.z = fmaf(p2, bf2f(u2.z), acc.z); acc.w = fmaf(p2, bf2f(u2.w), acc.w);
        acc.x = fmaf(p3, bf2f(u3.x), acc.x); acc.y = fmaf(p3, bf2f(u3.y), acc.y);
        acc.z = fmaf(p3, bf2f(u3.z), acc.z); acc.w = fmaf(p3, bf2f(u3.w), acc.w);
        dsum += (p0 + p1) + (p2 + p3);
    }
    for (; e < e1; ++e) {
        int s0 = csr_src[e];
        float e0 = as_[s0 * 4 + head] + ad;
        e0 = e0 > 0.f ? e0 : LRELU_SLOPE * e0;
        float p0 = __expf(e0);
        ushort4 u0 = *(const ushort4*)(h1 + (size_t)s0 * 256 + c0);
        acc.x = fmaf(p0, bf2f(u0.x), acc.x); acc.y = fmaf(p0, bf2f(u0.y), acc.y);
        acc.z = fmaf(p0, bf2f(u0.z), acc.z); acc.w = fmaf(p0, bf2f(u0.w), acc.w);
        dsum += p0;
    }
    const float inv = 1.f / (dsum + 1e-16f);
    const float4 b = *(const float4*)(bias + c0);
    float ox = acc.x * inv + b.x; ox = ox > 0.f ? ox : expm1f(ox);
    float oy = acc.y * inv + b.y; oy = oy > 0.f ? oy : expm1f(oy);
    float oz = acc.z * inv + b.z; oz = oz > 0.f ? oz : expm1f(oz);
    float ow = acc.w * inv + b.w; ow = ow > 0.f ? ow : expm1f(ow);
    ushort4 o;
    o.x = f2bf(ox); o.y = f2bf(oy); o.z = f2bf(oz); o.w = f2bf(ow);
    *(ushort4*)(outbf + (size_t)w * 256 + c0) = o;
}

// -------- layer-2 aggregation + scoring head, one wave per dst node --------
__global__ __launch_bounds__(256)
void aggregate_l2(const int* __restrict__ rowptr, const int* __restrict__ csr_src,
                  const ushort* __restrict__ h2, const float* __restrict__ as_,
                  const float* __restrict__ ad_, const float* __restrict__ b2,
                  const float* __restrict__ Wsv, const float* __restrict__ bs,
                  float* __restrict__ hout, float* __restrict__ scores, int N)
{
    int w = (blockIdx.x * blockDim.x + threadIdx.x) >> 6;
    int lane = threadIdx.x & 63;
    if (w >= N) return;
    const float ad = ad_[w];
    float acc, dsum;
    {   // implicit self-loop
        float el = as_[w] + ad;
        el = el > 0.f ? el : LRELU_SLOPE * el;
        float p = __expf(el);
        acc = p * bf2f(h2[(size_t)w * 64 + lane]);
        dsum = p;
    }
    int e = rowptr[w];
    const int e1 = rowptr[w + 1];
    for (; e + 3 < e1; e += 4) {
        int s0 = csr_src[e], s1 = csr_src[e + 1];
        int s2 = csr_src[e + 2], s3 = csr_src[e + 3];
        float e0 = as_[s0] + ad, e1v = as_[s1] + ad;
        float e2 = as_[s2] + ad, e3 = as_[s3] + ad;
        e0 = e0 > 0.f ? e0 : LRELU_SLOPE * e0;
        e1v = e1v > 0.f ? e1v : LRELU_SLOPE * e1v;
        e2 = e2 > 0.f ? e2 : LRELU_SLOPE * e2;
        e3 = e3 > 0.f ? e3 : LRELU_SLOPE * e3;
        float p0 = __expf(e0), p1 = __expf(e1v);
        float p2 = __expf(e2), p3 = __expf(e3);
        acc = fmaf(p0, bf2f(h2[(size_t)s0 * 64 + lane]), acc);
        acc = fmaf(p1, bf2f(h2[(size_t)s1 * 64 + lane]), acc);
        acc = fmaf(p2, bf2f(h2[(size_t)s2 * 64 + lane]), acc);
        acc = fmaf(p3, bf2f(h2[(size_t)s3 * 64 + lane]), acc);
        dsum += (p0 + p1) + (p2 + p3);
    }
    for (; e < e1; ++e) {
        int s0 = csr_src[e];
        float e0 = as_[s0] + ad;
        e0 = e0 > 0.f ? e0 : LRELU_SLOPE * e0;
        float p0 = __expf(e0);
        acc = fmaf(p0, bf2f(h2[(size_t)s0 * 64 + lane]), acc);
        dsum += p0;
    }
    float v = acc / (dsum + 1e-16f) + b2[lane];
    v = v > 0.f ? v : expm1f(v);
    hout[(size_t)w * 64 + lane] = v;
    float sc = v * Wsv[lane];
    #pragma unroll
    for (int off = 32; off; off >>= 1) sc += __shfl_down(sc, off);
    if (lane == 0) scores[w] = sc + bs[0];
}

// ---------------------------------------------------------------------------
extern "C" void kernel_launch(void* const* d_in, const int* in_sizes, int n_in,
                              void* d_out, int out_size, void* d_ws, size_t ws_size,
                              hipStream_t stream)
{
    const float* x    = (const float*)d_in[0];
    const int*   ei   = (const int*)d_in[1];
    const float* W1   = (const float*)d_in[2];
    const float* as1w = (const float*)d_in[3];
    const float* ad1w = (const float*)d_in[4];
    const float* b1   = (const float*)d_in[5];
    const float* W2   = (const float*)d_in[6];
    const float* as2w = (const float*)d_in[7];
    const float* ad2w = (const float*)d_in[8];
    const float* b2   = (const float*)d_in[9];
    const float* Ws   = (const float*)d_in[10];
    const float* bs   = (const float*)d_in[11];

    const int N  = in_sizes[0] / 128;   // 50000
    const int E  = in_sizes[1] / 2;     // 800000
    const int* esrc = ei;
    const int* edst = ei + E;

    // ---- workspace layout (16B-aligned chunks) ----
    ushort* h1bf  = (ushort*)d_ws;                       // N*256 bf16
    ushort* hl1bf = h1bf + (size_t)N * 256;              // N*256 bf16
    ushort* xbf   = hl1bf + (size_t)N * 256;             // N*128 bf16
    ushort* h2bf  = xbf + (size_t)N * 128;               // N*64 bf16
    ushort* bfr1  = h2bf + (size_t)N * 64;               // 32768
    ushort* bfr2  = bfr1 + 32768;                        // 16384
    float*  as1   = (float*)(bfr2 + 16384);              // N*4
    float*  ad1   = as1 + (size_t)N * 4;                 // N*4
    float*  as2   = ad1 + (size_t)N * 4;                 // N
    float*  ad2   = as2 + N;                             // N
    int*    deg    = (int*)(ad2 + N);                    // N
    int*    cursor = deg + N;                            // N
    int*    rowptr = cursor + N;                         // N+1 (+pad)
    int*    csr_src= rowptr + N + 4;                     // E

    float* hout   = (float*)d_out;                       // N*64
    float* scores = hout + (size_t)N * 64;               // N

    // ---------------- CSR build (shared by both layers) ----------------
    hipMemsetAsync(deg, 0, (size_t)N * sizeof(int), stream);
    degree_hist<<<(E + 255) / 256, 256, 0, stream>>>(edst, deg, E);
    scan_rowptr<<<1, 1024, 0, stream>>>(deg, rowptr, cursor, N);
    scatter_edges<<<(E + 255) / 256, 256, 0, stream>>>(
        esrc, edst, rowptr, cursor, csr_src, E);

    // ---------------- input conversion / weight pre-fragmentation -------
    conv_bf16<<<((size_t)N * 128 / 4 + 255) / 256, 256, 0, stream>>>(
        x, xbf, N * 128);
    prefrag<<<(16 * 4 * 64 + 255) / 256, 256, 0, stream>>>(W1, bfr1, 16, 4, 256);
    prefrag<<<(4 * 8 * 64 + 255) / 256, 256, 0, stream>>>(W2, bfr2, 4, 8, 64);

    // ---------------- layer 1 ----------------
    gemm_mfma<16, 4, 4><<<(N / 16 + 3) / 4, 256, 0, stream>>>(
        xbf, bfr1, h1bf, as1w, ad1w, as1, ad1, N);
    aggregate_l1<<<((size_t)N * 64 + 255) / 256, 256, 0, stream>>>(
        rowptr, csr_src, h1bf, as1, ad1, b1, hl1bf, N);

    // ---------------- layer 2 ----------------
    gemm_mfma<4, 8, 1><<<(N / 16 + 3) / 4, 256, 0, stream>>>(
        hl1bf, bfr2, h2bf, as2w, ad2w, as2, ad2, N);
    aggregate_l2<<<((size_t)N * 64 + 255) / 256, 256, 0, stream>>>(
        rowptr, csr_src, h2bf, as2, ad2, b2, Ws, bs, hout, scores, N);
}